// Round 1
// baseline (1077.049 us; speedup 1.0000x reference)
//
#include <hip/hip_runtime.h>
#include <math.h>

#define X_DIM   50
#define SEQ_LEN 230
#define BATCH   16384
#define KTRUE   150      // 3 * X_DIM
#define KPAD    160      // padded K for the GEMM
#define NOUT    1380     // Y_DIM * SEQ_LEN
#define NPAD    1408     // 22 * 64, padded N

// ---------------------------------------------------------------------------
// Kernel 1: pad w_out [1380,150] -> wp [1408,160] with zeros
// ---------------------------------------------------------------------------
__global__ __launch_bounds__(256) void prep_w(const float* __restrict__ w,
                                              float* __restrict__ wp) {
    int i = blockIdx.x * 256 + threadIdx.x;     // 0 .. NPAD*KPAD-1 (exact grid)
    int n = i / KPAD;
    int k = i - n * KPAD;
    float v = 0.f;
    if (n < NOUT && k < KTRUE) v = w[n * KTRUE + k];
    wp[i] = v;
}

// ---------------------------------------------------------------------------
// Kernel 2: depthwise conv (k=3,6,12) + bias + max over valid positions.
// One thread per (batch, channel). flat[b][3c+j] = max_j, flat[b][150..159]=0.
// ---------------------------------------------------------------------------
__global__ __launch_bounds__(256) void conv_max(
    const float* __restrict__ x,   // [B, 230, 50]
    const float* __restrict__ w1, const float* __restrict__ b1,
    const float* __restrict__ w2, const float* __restrict__ b2,
    const float* __restrict__ w3, const float* __restrict__ b3,
    float* __restrict__ flat) {    // [B, KPAD]
    int g = blockIdx.x * 256 + threadIdx.x;     // 0 .. B*50-1 (exact grid)
    int b = g / X_DIM;
    int c = g - b * X_DIM;

    const float* p = x + (size_t)b * (SEQ_LEN * X_DIM) + c;

    float W1c[3], W2c[6], W3c[12];
#pragma unroll
    for (int i = 0; i < 3; ++i)  W1c[i] = w1[c * 3 + i];
#pragma unroll
    for (int i = 0; i < 6; ++i)  W2c[i] = w2[c * 6 + i];
#pragma unroll
    for (int i = 0; i < 12; ++i) W3c[i] = w3[c * 12 + i];

    float m1 = -1e30f, m2 = -1e30f, m3 = -1e30f;
    float buf[12];

    // ---- prologue: t = 0..11 (window filling; compile-time guards) ----
#pragma unroll
    for (int t = 0; t < 12; ++t) {
        float v = p[t * X_DIM];
        buf[t] = v;
        if (t >= 2) {
            float s = fmaf(buf[t - 2], W1c[0], fmaf(buf[t - 1], W1c[1], v * W1c[2]));
            m1 = fmaxf(m1, s);
        }
        if (t >= 5) {
            float s = 0.f;
#pragma unroll
            for (int i = 0; i < 6; ++i) s = fmaf(buf[t - 5 + i], W2c[i], s);
            m2 = fmaxf(m2, s);
        }
        if (t == 11) {
            float s = 0.f;
#pragma unroll
            for (int i = 0; i < 12; ++i) s = fmaf(buf[i], W3c[i], s);
            m3 = fmaxf(m3, s);
        }
    }

    // ---- main: t = 12..227 in 18 chunks of 12 (ring indices static) ----
    const float* q = p + 12 * X_DIM;
#pragma unroll 2
    for (int it = 0; it < 18; ++it) {
#pragma unroll
        for (int j = 0; j < 12; ++j) {
            float v = q[j * X_DIM];
            buf[j] = v;
            float s1 = fmaf(buf[(j + 10) % 12], W1c[0],
                       fmaf(buf[(j + 11) % 12], W1c[1], v * W1c[2]));
            m1 = fmaxf(m1, s1);
            float s2 = 0.f;
#pragma unroll
            for (int i = 0; i < 6; ++i) s2 = fmaf(buf[(j + 7 + i) % 12], W2c[i], s2);
            m2 = fmaxf(m2, s2);
            float s3 = 0.f;
#pragma unroll
            for (int i = 0; i < 12; ++i) s3 = fmaf(buf[(j + 1 + i) % 12], W3c[i], s3);
            m3 = fmaxf(m3, s3);
        }
        q += 12 * X_DIM;
    }

    // ---- epilogue: t = 228, 229 (j = 0, 1) ----
#pragma unroll
    for (int j = 0; j < 2; ++j) {
        float v = q[j * X_DIM];
        buf[j] = v;
        float s1 = fmaf(buf[(j + 10) % 12], W1c[0],
                   fmaf(buf[(j + 11) % 12], W1c[1], v * W1c[2]));
        m1 = fmaxf(m1, s1);
        float s2 = 0.f;
#pragma unroll
        for (int i = 0; i < 6; ++i) s2 = fmaf(buf[(j + 7 + i) % 12], W2c[i], s2);
        m2 = fmaxf(m2, s2);
        float s3 = 0.f;
#pragma unroll
        for (int i = 0; i < 12; ++i) s3 = fmaf(buf[(j + 1 + i) % 12], W3c[i], s3);
        m3 = fmaxf(m3, s3);
    }

    // bias is position-invariant: max(conv+b) = max(conv)+b
    size_t base = (size_t)b * KPAD + 3 * c;
    flat[base + 0] = m1 + b1[c];
    flat[base + 1] = m2 + b2[c];
    flat[base + 2] = m3 + b3[c];
    if (c < KPAD - KTRUE) flat[(size_t)b * KPAD + KTRUE + c] = 0.f;  // zero pad
}

// ---------------------------------------------------------------------------
// Kernel 3: fp32 GEMM  out[b,n] = sum_k flat[b,k] * wp[n,k] + bias[n]
// 128x128 block tile, 8x8 per thread, BK=16, 256 threads.
// ---------------------------------------------------------------------------
#define BM 128
#define BN 128
#define BK 16

__global__ __launch_bounds__(256) void gemm_k(
    const float* __restrict__ A,    // flat [BATCH, KPAD]
    const float* __restrict__ Wp,   // [NPAD, KPAD]
    const float* __restrict__ bias, // [NOUT]
    float* __restrict__ out) {      // [BATCH, NOUT]
    __shared__ float As[BK][BM];
    __shared__ float Bs[BK][BN];

    int tid = threadIdx.x;
    int bn = blockIdx.x * BN;
    int bm = blockIdx.y * BM;
    int tm = tid >> 4;          // 0..15
    int tn = tid & 15;          // 0..15

    int lrow = tid >> 2;        // 0..63
    int lk4  = (tid & 3) * 4;   // 0,4,8,12

    const float* Ap = A  + (size_t)(bm + lrow) * KPAD + lk4;
    const float* Bp = Wp + (size_t)(bn + lrow) * KPAD + lk4;

    float acc[8][8] = {};

    for (int k0 = 0; k0 < KPAD; k0 += BK) {
        float4 a0 = *(const float4*)(Ap + k0);
        float4 a1 = *(const float4*)(Ap + (size_t)64 * KPAD + k0);
        float4 bb0 = *(const float4*)(Bp + k0);
        float4 bb1 = *(const float4*)(Bp + (size_t)64 * KPAD + k0);

        __syncthreads();   // previous chunk's compute done before overwrite
        As[lk4 + 0][lrow] = a0.x;  As[lk4 + 1][lrow] = a0.y;
        As[lk4 + 2][lrow] = a0.z;  As[lk4 + 3][lrow] = a0.w;
        As[lk4 + 0][lrow + 64] = a1.x;  As[lk4 + 1][lrow + 64] = a1.y;
        As[lk4 + 2][lrow + 64] = a1.z;  As[lk4 + 3][lrow + 64] = a1.w;
        Bs[lk4 + 0][lrow] = bb0.x;  Bs[lk4 + 1][lrow] = bb0.y;
        Bs[lk4 + 2][lrow] = bb0.z;  Bs[lk4 + 3][lrow] = bb0.w;
        Bs[lk4 + 0][lrow + 64] = bb1.x;  Bs[lk4 + 1][lrow + 64] = bb1.y;
        Bs[lk4 + 2][lrow + 64] = bb1.z;  Bs[lk4 + 3][lrow + 64] = bb1.w;
        __syncthreads();

#pragma unroll
        for (int k = 0; k < BK; ++k) {
            float4 av0 = *(const float4*)&As[k][tm * 8];
            float4 av1 = *(const float4*)&As[k][tm * 8 + 4];
            float4 bv0 = *(const float4*)&Bs[k][tn * 8];
            float4 bv1 = *(const float4*)&Bs[k][tn * 8 + 4];
            float a[8] = {av0.x, av0.y, av0.z, av0.w, av1.x, av1.y, av1.z, av1.w};
            float bfr[8] = {bv0.x, bv0.y, bv0.z, bv0.w, bv1.x, bv1.y, bv1.z, bv1.w};
#pragma unroll
            for (int i = 0; i < 8; ++i)
#pragma unroll
                for (int jj = 0; jj < 8; ++jj)
                    acc[i][jj] = fmaf(a[i], bfr[jj], acc[i][jj]);
        }
    }

    // epilogue: add bias, store float4 (NOUT % 4 == 0, so guard is exact)
#pragma unroll
    for (int i = 0; i < 8; ++i) {
        size_t m = (size_t)(bm + tm * 8 + i);
#pragma unroll
        for (int j4 = 0; j4 < 8; j4 += 4) {
            int n = bn + tn * 8 + j4;
            if (n < NOUT) {
                float4 r;
                r.x = acc[i][j4 + 0] + bias[n + 0];
                r.y = acc[i][j4 + 1] + bias[n + 1];
                r.z = acc[i][j4 + 2] + bias[n + 2];
                r.w = acc[i][j4 + 3] + bias[n + 3];
                *(float4*)(out + m * NOUT + n) = r;
            }
        }
    }
}

// ---------------------------------------------------------------------------
extern "C" void kernel_launch(void* const* d_in, const int* in_sizes, int n_in,
                              void* d_out, int out_size, void* d_ws, size_t ws_size,
                              hipStream_t stream) {
    const float* seq   = (const float*)d_in[0];
    const float* w1    = (const float*)d_in[1];
    const float* b1    = (const float*)d_in[2];
    const float* w2    = (const float*)d_in[3];
    const float* b2    = (const float*)d_in[4];
    const float* w3    = (const float*)d_in[5];
    const float* b3    = (const float*)d_in[6];
    const float* w_out = (const float*)d_in[7];
    const float* b_out = (const float*)d_in[8];
    float* out = (float*)d_out;

    // workspace layout: flat [BATCH*KPAD] fp32, then wp [NPAD*KPAD] fp32
    float* flat = (float*)d_ws;
    float* wp   = flat + (size_t)BATCH * KPAD;

    prep_w<<<(NPAD * KPAD) / 256, 256, 0, stream>>>(w_out, wp);
    conv_max<<<(BATCH * X_DIM) / 256, 256, 0, stream>>>(
        seq, w1, b1, w2, b2, w3, b3, flat);
    gemm_k<<<dim3(NPAD / BN, BATCH / BM), 256, 0, stream>>>(flat, wp, b_out, out);
}